// Round 2
// baseline (415.701 us; speedup 1.0000x reference)
//
#include <hip/hip_runtime.h>
#include <cstdint>
#include <cstddef>

constexpr int T_ = 128;
constexpr int S_ = 512;
constexpr int B_ = 256;
constexpr int START_ = T_ - 3;  // 125
constexpr int STOP_  = T_ - 2;  // 126

// Barrier that only drains LDS (lgkmcnt), NOT vmcnt: global ph-stores and
// e-prefetch loads legally stay in flight across it (thread-private data).
__device__ __forceinline__ void lds_barrier() {
  asm volatile("s_waitcnt lgkmcnt(0)\n\ts_barrier" ::: "memory");
}

// readlane: wave-uniform lane index (SGPR) -> ~VALU-speed broadcast.
__device__ __forceinline__ float readlane_f(float v, int sl) {
  return __int_as_float(__builtin_amdgcn_readlane(__float_as_int(v), sl));
}

// forced 3-input max (VOP3). Inputs are finite (no NaN in this problem):
// v_max3_f32(a,b,c) == fmaxf(fmaxf(a,b),c) bit-exactly.
__device__ __forceinline__ float max3f(float a, float b, float c) {
  float d;
  asm("v_max3_f32 %0, %1, %2, %3" : "=v"(d) : "v"(a), "v"(b), "v"(c));
  return d;
}

// max-reduce over the 16 ig-lanes (lane bits [0,4)) in pure row-DPP:
// quad xor1 (0xB1), quad xor2 (0x4E), row_half_mirror (0x141: l^7 == l^4
// once quad-uniform), row_mirror (0x140: l^15 == l^8 once 8-uniform).
// DPP rows are 16 lanes on gfx9 -> each 16-lane group reduces independently.
__device__ __forceinline__ float ig16_rmax(float m) {
  int x = __builtin_amdgcn_mov_dpp(__float_as_int(m), 0xB1, 0xF, 0xF, true);
  m = fmaxf(m, __int_as_float(x));
  x = __builtin_amdgcn_mov_dpp(__float_as_int(m), 0x4E, 0xF, 0xF, true);
  m = fmaxf(m, __int_as_float(x));
  x = __builtin_amdgcn_mov_dpp(__float_as_int(m), 0x141, 0xF, 0xF, true);
  m = fmaxf(m, __int_as_float(x));
  x = __builtin_amdgcn_mov_dpp(__float_as_int(m), 0x140, 0xF, 0xF, true);
  m = fmaxf(m, __int_as_float(x));
  return m;
}

// padded part layout: value i at float offset i + 4*(i>>3).
// Thread ig's 8-float granule starts at float 12*ig (byte 48*ig, 16B-aligned
// for b128 x2). Banks: granule ig covers banks [12ig, 12ig+3] mod 32 -> ig
// and ig+8 alias (2-way, free per m136); 4-fold same-address lane dup is
// LDS broadcast. j-pair writes {2jg,2jg+1} never straddle a pad (8-aligned
// groups, pairs are even-based).
__device__ __forceinline__ int pidx(int i) { return i + 4 * (i >> 3); }

// ---------------------------------------------------------------------------
// Forward: value-only Viterbi recursion, stores part_hist (S,B,T) fp32.
// R9 CHANGE vs R8: ci=8 / cj=2 split at 1024 threads. R8 (ci=16/cj=1)
// measured 930 cyc/step: per-thread 64 B LDS read x 1024 = 64 KB/step
// through the 128 B/cyc LDS return bus = 512 cyc -> LDS-BUS-bound (broadcast
// dedups bank conflicts, not bus bandwidth). cj=2 halves bus to 256 cyc;
// VALU rises to ~52/thread (16 add + 2x4 max3-tree + 4 DPP stages x 2 j)
// -> ~420 issue-cyc/SIMD, still under the bus+latency skeleton.
// Bit-exact vs reference: max exactly associative (any reduce order), fl
// monotone => max_i fl(fl(p+tr)+e) == fl(max_i fl(p+tr) + e).
// ---------------------------------------------------------------------------
__global__ __launch_bounds__(1024, 4) void viterbi_forward(
    const float* __restrict__ feats,   // (B,S,T)
    const float* __restrict__ trans,   // (T,T)
    float* __restrict__ ph)            // (S,B,T) workspace
{
  const int b    = blockIdx.x;
  const int tid  = threadIdx.x;
  const int lane = tid & 63;
  const int ig   = lane & 15;          // i-chunk: i in [8ig, 8ig+8)
  const int jg   = tid >> 4;           // 0..63: output column pair {2jg,2jg+1}
  const int j0   = 2 * jg;

  __shared__ alignas(16) float part[2][192];

  // trans rows 8ig..8ig+8, column pair j0 (float2 each; 16 VGPRs, fixed)
  float2 tc[8];
  #pragma unroll
  for (int ii = 0; ii < 8; ++ii)
    tc[ii] = *(const float2*)&trans[(8 * ig + ii) * T_ + j0];

  const float* fb = feats + (size_t)b * S_ * T_;
  const int woff  = j0 + 4 * (jg >> 2);   // pidx(2jg); pair stays in-granule

  // t = 0: part0 = emit[0] + trans[START,:]
  float2 e0 = *(const float2*)&fb[j0];
  float2 ts = *(const float2*)&trans[START_ * T_ + j0];
  float2 p0 = make_float2(e0.x + ts.x, e0.y + ts.y);
  if (ig == 0) {
    *(float2*)&part[0][woff] = p0;
    *(float2*)&ph[(size_t)b * T_ + j0] = p0;
  }
  __syncthreads();

  auto stepf = [&](int t, float2 e2) {
    const float* P = part[(t - 1) & 1];
    float4 pa = *(const float4*)&P[12 * ig];
    float4 pb = *(const float4*)&P[12 * ig + 4];
    const float pv[8] = {pa.x, pa.y, pa.z, pa.w, pb.x, pb.y, pb.z, pb.w};
    // column j0
    float x0 = pv[0] + tc[0].x, x1 = pv[1] + tc[1].x,
          x2 = pv[2] + tc[2].x, x3 = pv[3] + tc[3].x,
          x4 = pv[4] + tc[4].x, x5 = pv[5] + tc[5].x,
          x6 = pv[6] + tc[6].x, x7 = pv[7] + tc[7].x;
    // column j0+1
    float y0 = pv[0] + tc[0].y, y1 = pv[1] + tc[1].y,
          y2 = pv[2] + tc[2].y, y3 = pv[3] + tc[3].y,
          y4 = pv[4] + tc[4].y, y5 = pv[5] + tc[5].y,
          y6 = pv[6] + tc[6].y, y7 = pv[7] + tc[7].y;
    float mx = fmaxf(max3f(max3f(x0, x1, x2), max3f(x3, x4, x5), x6), x7);
    float my = fmaxf(max3f(max3f(y0, y1, y2), max3f(y3, y4, y5), y6), y7);
    mx = ig16_rmax(mx);                 // all 16 ig-lanes hold max over i
    my = ig16_rmax(my);
    float2 np = make_float2(mx + e2.x, my + e2.y);
    if (ig == 0) *(float2*)&part[t & 1][woff] = np;
    lds_barrier();
    if (ig == 0)
      *(float2*)&ph[((size_t)t * B_ + b) * T_ + j0] = np;  // off critical path
  };

  // emission prefetch: 8 rows in flight (named A/B groups of 4, no rotation)
  float2 EA[4], EB[4];
  #pragma unroll
  for (int u = 0; u < 4; ++u)
    EA[u] = *(const float2*)&fb[(size_t)(1 + u) * T_ + j0];

  for (int t0 = 1; t0 < S_; t0 += 8) {
    #pragma unroll
    for (int u = 0; u < 4; ++u) {
      int tr = t0 + 4 + u; if (tr > S_ - 1) tr = S_ - 1;
      EB[u] = *(const float2*)&fb[(size_t)tr * T_ + j0];
    }
    #pragma unroll
    for (int u = 0; u < 4; ++u) { int t = t0 + u; if (t < S_) stepf(t, EA[u]); }
    #pragma unroll
    for (int u = 0; u < 4; ++u) {
      int tr = t0 + 8 + u; if (tr > S_ - 1) tr = S_ - 1;
      EA[u] = *(const float2*)&fb[(size_t)tr * T_ + j0];
    }
    #pragma unroll
    for (int u = 0; u < 4; ++u) { int t = t0 + 4 + u; if (t < S_) stepf(t, EB[u]); }
  }
}

// ---------------------------------------------------------------------------
// Trace: one wave (64 lanes) per b, grid 256. UNCHANGED from R8 (isolate
// the forward experiment). bp recomputed on-path only via equality-ballot;
// bit-exact first-occurrence argmax vs reference.
// ---------------------------------------------------------------------------
constexpr int CH_ = 8;   // chunk size (steps per buffer)
constexpr int TS_ = 130; // transT row stride (even: float2-aligned, 2-way ok)

__global__ __launch_bounds__(64, 1) void viterbi_trace(
    const float* __restrict__ feats,   // (B,S,T)
    const void*  __restrict__ mask,    // (B,S) dtype detected at runtime
    const float* __restrict__ trans,   // (T,T)
    const float* __restrict__ ph,      // (S,B,T)
    int* __restrict__ out)             // (B,S) int32
{
  const int b    = blockIdx.x;
  const int lane = threadIdx.x;

  __shared__ alignas(16) float transT[T_ * TS_];  // transT[j*TS+i] = trans[i][j]
  #pragma unroll 4
  for (int g = lane; g < T_ * T_; g += 64) {
    int i = g >> 7, jj = g & (T_ - 1);
    transT[jj * TS_ + i] = trans[g];
  }
  __syncthreads();

  // ---- sequence length (mask dtype: uint8 / float32 / int32) ----
  int len = 0;
  {
    const int w0 = *(const int*)mask;  // element (0,0) is always true
    if (w0 == 0x01010101) {
      const unsigned char* m = (const unsigned char*)mask + (size_t)b * S_;
      for (int s = lane; s < S_; s += 64) len += (m[s] != 0);
    } else if (w0 == 0x3F800000) {
      const float* m = (const float*)mask + (size_t)b * S_;
      for (int s = lane; s < S_; s += 64) len += (m[s] != 0.0f);
    } else {
      const int* m = (const int*)mask + (size_t)b * S_;
      for (int s = lane; s < S_; s += 64) len += (m[s] != 0);
    }
    #pragma unroll
    for (int o = 32; o > 0; o >>= 1) len += __shfl_xor(len, o);
  }
  const int lp = len - 1;              // last valid position (>= S/2-1)

  // ---- final pointer: first argmax_i(ph_lp[i] + trans[i][STOP]) ----
  const float2 L = *(const float2*)(ph + ((size_t)lp * B_ + b) * T_ + 2 * lane);
  float v0 = L.x + transT[STOP_ * TS_ + 2 * lane];
  float v1 = L.y + transT[STOP_ * TS_ + 2 * lane + 1];
  float mx = fmaxf(v0, v1);
  #pragma unroll
  for (int o = 32; o > 0; o >>= 1) mx = fmaxf(mx, __shfl_xor(mx, o));
  {
    unsigned long long g0 = __ballot(v0 == mx);
    unsigned long long g1 = __ballot(v1 == mx);
    int p0 = g0 ? 2 * (__ffsll(g0) - 1)     : (1 << 30);
    int p1 = g1 ? 2 * (__ffsll(g1) - 1) + 1 : (1 << 30);
    int pointer = min(p0, p1);

    // ---- masked tail: out[k]=0 for lp<k<S-1; out[S-1]=out[lp]=pointer ----
    for (int k = lp + 1 + lane; k <= S_ - 2; k += 64) out[b * S_ + k] = 0;
    if (lane == 0) {
      out[b * S_ + (S_ - 1)] = pointer;
      if (lp < S_ - 1) out[b * S_ + lp] = pointer;
    }

    // ---- chase k = lp-1 .. 0 ----
    int   ptr = pointer;
    float tg  = readlane_f((ptr & 1) ? L.y : L.x, ptr >> 1);  // ph[lp][ptr]
    const float* fb = feats + (size_t)b * S_ * T_;
    const float2 FL = *(const float2*)(fb + (size_t)lp * T_ + 2 * lane);
    float e = readlane_f((ptr & 1) ? FL.y : FL.x, ptr >> 1);  // feats[lp][ptr]

    float2 PA[CH_], FA[CH_], PB[CH_], FB[CH_];

    auto issue = [&](float2 (&P)[CH_], float2 (&F)[CH_], int k0) {
      #pragma unroll
      for (int s = 0; s < CH_; ++s) {
        int k = k0 - s; if (k < 0) k = 0;     // clamped slots never used
        P[s] = *(const float2*)(ph + ((size_t)k * B_ + b) * T_ + 2 * lane);
        F[s] = *(const float2*)(fb + (size_t)k * T_ + 2 * lane);
      }
    };
    auto process = [&](const float2 (&P)[CH_], const float2 (&F)[CH_], int k0) {
      #pragma unroll
      for (int s = 0; s < CH_; ++s) {
        const int k = k0 - s;
        if (k >= 0) {
          // candidates c_i = fl(fl(ph_k[i]+trans[i,ptr]) + e), i = 2l, 2l+1
          const float2 tr = *(const float2*)(transT + ptr * TS_ + 2 * lane);
          float cx = (P[s].x + tr.x) + e;
          float cy = (P[s].y + tr.y) + e;
          unsigned long long q0 = __ballot(cx == tg);
          unsigned long long q1 = __ballot(cy == tg);
          int a0 = q0 ? 2 * (__ffsll(q0) - 1)     : (1 << 30);
          int a1 = q1 ? 2 * (__ffsll(q1) - 1) + 1 : (1 << 30);
          ptr = min(a0, a1);
          if (lane == 0) out[b * S_ + k] = ptr;
          // next step (k-1) targets ph_k[ptr], feats[k][ptr]
          tg = readlane_f((ptr & 1) ? P[s].y : P[s].x, ptr >> 1);
          e  = readlane_f((ptr & 1) ? F[s].y : F[s].x, ptr >> 1);
        }
      }
    };

    issue(PA, FA, lp - 1);
    for (int k0 = lp - 1; k0 >= 0; k0 -= 2 * CH_) {
      issue(PB, FB, k0 - CH_);
      process(PA, FA, k0);
      issue(PA, FA, k0 - 2 * CH_);
      process(PB, FB, k0 - CH_);
    }
  }
}

extern "C" void kernel_launch(void* const* d_in, const int* in_sizes, int n_in,
                              void* d_out, int out_size, void* d_ws, size_t ws_size,
                              hipStream_t stream) {
  const float* feats = (const float*)d_in[0];   // (B,S,T) fp32
  const void*  mask  = d_in[1];                 // (B,S) bool-ish
  const float* trans = (const float*)d_in[2];   // (T,T) fp32
  float* ph = (float*)d_ws;                     // (S,B,T) fp32 = 64 MB
  int*   out = (int*)d_out;                     // (B,S) int32

  viterbi_forward<<<dim3(B_), dim3(1024), 0, stream>>>(feats, trans, ph);
  viterbi_trace  <<<dim3(B_), dim3(64), 0, stream>>>(feats, mask, trans, ph, out);
}

// Round 3
// 360.704 us; speedup vs baseline: 1.1525x; 1.1525x over previous
//
#include <hip/hip_runtime.h>
#include <cstdint>
#include <cstddef>

constexpr int T_ = 128;
constexpr int S_ = 512;
constexpr int B_ = 256;
constexpr int START_ = T_ - 3;  // 125
constexpr int STOP_  = T_ - 2;  // 126

typedef float v2f __attribute__((ext_vector_type(2)));

// Barrier that only drains LDS (lgkmcnt), NOT vmcnt: global ph-stores and
// e-prefetch loads legally stay in flight across it (thread-private data).
__device__ __forceinline__ void lds_barrier() {
  asm volatile("s_waitcnt lgkmcnt(0)\n\ts_barrier" ::: "memory");
}

// readlane: wave-uniform lane index (SGPR) -> ~VALU-speed broadcast.
__device__ __forceinline__ float readlane_f(float v, int sl) {
  return __int_as_float(__builtin_amdgcn_readlane(__float_as_int(v), sl));
}

// forced 3-input max (VOP3). Inputs are finite (no NaN in this problem):
// v_max3_f32(a,b,c) == fmaxf(fmaxf(a,b),c) bit-exactly.
__device__ __forceinline__ float max3f(float a, float b, float c) {
  float d;
  asm("v_max3_f32 %0, %1, %2, %3" : "=v"(d) : "v"(a), "v"(b), "v"(c));
  return d;
}

// max-reduce over the 8 ig-lanes (lane bits [0,3)) in pure row-DPP:
// quad xor1 (0xB1), quad xor2 (0x4E), row_half_mirror (0x141: reverses each
// 8-lane half; == xor4 once quad-uniform). All 8 lanes end with the max.
__device__ __forceinline__ float ig8_rmax(float m) {
  int x = __builtin_amdgcn_mov_dpp(__float_as_int(m), 0xB1, 0xF, 0xF, true);
  m = fmaxf(m, __int_as_float(x));
  x = __builtin_amdgcn_mov_dpp(__float_as_int(m), 0x4E, 0xF, 0xF, true);
  m = fmaxf(m, __int_as_float(x));
  x = __builtin_amdgcn_mov_dpp(__float_as_int(m), 0x141, 0xF, 0xF, true);
  m = fmaxf(m, __int_as_float(x));
  return m;
}

// padded part layout: value i at float offset i + 4*(i>>4).
// Thread ig's 16-float granule = floats [20ig, 20ig+16) (byte 80ig, 16B
// aligned). Quad-banks 20ig%32 = {0,20,8,28,16,4,24,12}+0..3: the 8 granule
// quads are disjoint and cover all 32 banks -> conflict-free; 8-fold
// same-address lane duplication is LDS broadcast (free).
__device__ __forceinline__ int pidx(int i) { return i + 4 * (i >> 4); }

// ---------------------------------------------------------------------------
// Forward: value-only Viterbi recursion, stores part_hist (S,B,T) fp32.
// R10 vs R9: REVERT to R8's winning split (ci=16/cj=1, 1024 th, 198 us;
// R9's ci=8/cj=2 regressed to 272 us -> VALU-issue-bound, LDS-bus theory
// falsified). Then cut VALU further:
//  (a) PIN the trans tile in VGPRs via empty asm (R8 reported VGPR=24,
//      too few for tc[16]+E[8] -> compiler was re-loading trans inside the
//      loop; the opaque asm makes remat illegal). Falsifiable: VGPR >= 40.
//  (b) pack the 16 adds as 8 v_pk_add_f32 (v2f ext-vector adds).
//  (c) shift-form addressing off precomputed bases for ph/feats.
// Core VALU/step: 8 pk_add + 8 max3-tree + 3 DPP mov + 3 fmax + 1 add ~ 23.
// Bit-exact vs reference: max exactly associative (any reduce order), fl
// monotone => max_i fl(fl(p+tr)+e) == fl(max_i fl(p+tr) + e); pk_add is
// IEEE identical to scalar v_add_f32.
// ---------------------------------------------------------------------------
__global__ __launch_bounds__(1024, 4) void viterbi_forward(
    const float* __restrict__ feats,   // (B,S,T)
    const float* __restrict__ trans,   // (T,T)
    float* __restrict__ ph)            // (S,B,T) workspace
{
  const int b    = blockIdx.x;
  const int tid  = threadIdx.x;
  const int lane = tid & 63;
  const int ig   = lane & 7;           // i-chunk: i in [16ig, 16ig+16)
  const int j    = tid >> 3;           // 0..127: this thread's output column

  __shared__ alignas(16) float part[2][160];

  // trans column j, rows 16ig..16ig+16, packed into 8 VGPR pairs
  v2f tc2[8];
  #pragma unroll
  for (int ii = 0; ii < 8; ++ii) {
    tc2[ii][0] = trans[(16 * ig + 2 * ii)     * T_ + j];
    tc2[ii][1] = trans[(16 * ig + 2 * ii + 1) * T_ + j];
  }
  // Pin: value escapes through opaque asm -> no remat/reload in the loop.
  #pragma unroll
  for (int ii = 0; ii < 8; ++ii) asm volatile("" : "+v"(tc2[ii]));

  const float* fb = feats + (size_t)b * S_ * T_;
  const float* fe = fb + j;                 // emission base for column j
  float*       pw = ph + (size_t)b * T_ + j; // ph store base for column j
  const int woff  = pidx(j);

  // t = 0: part0 = emit[0] + trans[START,:]
  float p00 = fb[j] + trans[START_ * T_ + j];
  if (ig == 0) {
    part[0][woff] = p00;
    pw[0] = p00;
  }
  __syncthreads();

  auto stepf = [&](int t, float e) {
    const float4* p4 = (const float4*)part[(t - 1) & 1];
    float4 pa = p4[5 * ig];
    float4 pb = p4[5 * ig + 1];
    float4 pc = p4[5 * ig + 2];
    float4 pd = p4[5 * ig + 3];
    v2f r0 = v2f{pa.x, pa.y} + tc2[0];
    v2f r1 = v2f{pa.z, pa.w} + tc2[1];
    v2f r2 = v2f{pb.x, pb.y} + tc2[2];
    v2f r3 = v2f{pb.z, pb.w} + tc2[3];
    v2f r4 = v2f{pc.x, pc.y} + tc2[4];
    v2f r5 = v2f{pc.z, pc.w} + tc2[5];
    v2f r6 = v2f{pd.x, pd.y} + tc2[6];
    v2f r7 = v2f{pd.z, pd.w} + tc2[7];
    float m0 = max3f(r0[0], r0[1], r1[0]);
    float m1 = max3f(r1[1], r2[0], r2[1]);
    float m2 = max3f(r3[0], r3[1], r4[0]);
    float m3 = max3f(r4[1], r5[0], r5[1]);
    float m4 = max3f(r6[0], r6[1], r7[0]);
    float n0 = max3f(m0, m1, m2);
    float n1 = max3f(m3, m4, r7[1]);
    float mm = ig8_rmax(fmaxf(n0, n1));   // all 8 ig-lanes hold max over i
    float np = mm + e;
    if (ig == 0) part[t & 1][woff] = np;
    lds_barrier();
    if (ig == 0)
      pw[(size_t)t << 15] = np;           // B_*T_ = 32768; off critical path
  };

  // emission prefetch: 8 rows in flight (named A/B groups of 4, no rotation)
  float EA[4], EB[4];
  #pragma unroll
  for (int u = 0; u < 4; ++u)
    EA[u] = fe[(size_t)(1 + u) << 7];

  for (int t0 = 1; t0 < S_; t0 += 8) {
    #pragma unroll
    for (int u = 0; u < 4; ++u) {
      int tr = t0 + 4 + u; if (tr > S_ - 1) tr = S_ - 1;
      EB[u] = fe[(size_t)tr << 7];
    }
    #pragma unroll
    for (int u = 0; u < 4; ++u) { int t = t0 + u; if (t < S_) stepf(t, EA[u]); }
    #pragma unroll
    for (int u = 0; u < 4; ++u) {
      int tr = t0 + 8 + u; if (tr > S_ - 1) tr = S_ - 1;
      EA[u] = fe[(size_t)tr << 7];
    }
    #pragma unroll
    for (int u = 0; u < 4; ++u) { int t = t0 + 4 + u; if (t < S_) stepf(t, EB[u]); }
  }
}

// ---------------------------------------------------------------------------
// Trace: one wave (64 lanes) per b, grid 256. UNCHANGED (isolate the
// forward experiment). bp recomputed on-path only via equality-ballot;
// bit-exact first-occurrence argmax vs reference.
// ---------------------------------------------------------------------------
constexpr int CH_ = 8;   // chunk size (steps per buffer)
constexpr int TS_ = 130; // transT row stride (even: float2-aligned, 2-way ok)

__global__ __launch_bounds__(64, 1) void viterbi_trace(
    const float* __restrict__ feats,   // (B,S,T)
    const void*  __restrict__ mask,    // (B,S) dtype detected at runtime
    const float* __restrict__ trans,   // (T,T)
    const float* __restrict__ ph,      // (S,B,T)
    int* __restrict__ out)             // (B,S) int32
{
  const int b    = blockIdx.x;
  const int lane = threadIdx.x;

  __shared__ alignas(16) float transT[T_ * TS_];  // transT[j*TS+i] = trans[i][j]
  #pragma unroll 4
  for (int g = lane; g < T_ * T_; g += 64) {
    int i = g >> 7, jj = g & (T_ - 1);
    transT[jj * TS_ + i] = trans[g];
  }
  __syncthreads();

  // ---- sequence length (mask dtype: uint8 / float32 / int32) ----
  int len = 0;
  {
    const int w0 = *(const int*)mask;  // element (0,0) is always true
    if (w0 == 0x01010101) {
      const unsigned char* m = (const unsigned char*)mask + (size_t)b * S_;
      for (int s = lane; s < S_; s += 64) len += (m[s] != 0);
    } else if (w0 == 0x3F800000) {
      const float* m = (const float*)mask + (size_t)b * S_;
      for (int s = lane; s < S_; s += 64) len += (m[s] != 0.0f);
    } else {
      const int* m = (const int*)mask + (size_t)b * S_;
      for (int s = lane; s < S_; s += 64) len += (m[s] != 0);
    }
    #pragma unroll
    for (int o = 32; o > 0; o >>= 1) len += __shfl_xor(len, o);
  }
  const int lp = len - 1;              // last valid position (>= S/2-1)

  // ---- final pointer: first argmax_i(ph_lp[i] + trans[i][STOP]) ----
  const float2 L = *(const float2*)(ph + ((size_t)lp * B_ + b) * T_ + 2 * lane);
  float v0 = L.x + transT[STOP_ * TS_ + 2 * lane];
  float v1 = L.y + transT[STOP_ * TS_ + 2 * lane + 1];
  float mx = fmaxf(v0, v1);
  #pragma unroll
  for (int o = 32; o > 0; o >>= 1) mx = fmaxf(mx, __shfl_xor(mx, o));
  {
    unsigned long long g0 = __ballot(v0 == mx);
    unsigned long long g1 = __ballot(v1 == mx);
    int p0 = g0 ? 2 * (__ffsll(g0) - 1)     : (1 << 30);
    int p1 = g1 ? 2 * (__ffsll(g1) - 1) + 1 : (1 << 30);
    int pointer = min(p0, p1);

    // ---- masked tail: out[k]=0 for lp<k<S-1; out[S-1]=out[lp]=pointer ----
    for (int k = lp + 1 + lane; k <= S_ - 2; k += 64) out[b * S_ + k] = 0;
    if (lane == 0) {
      out[b * S_ + (S_ - 1)] = pointer;
      if (lp < S_ - 1) out[b * S_ + lp] = pointer;
    }

    // ---- chase k = lp-1 .. 0 ----
    int   ptr = pointer;
    float tg  = readlane_f((ptr & 1) ? L.y : L.x, ptr >> 1);  // ph[lp][ptr]
    const float* fb = feats + (size_t)b * S_ * T_;
    const float2 FL = *(const float2*)(fb + (size_t)lp * T_ + 2 * lane);
    float e = readlane_f((ptr & 1) ? FL.y : FL.x, ptr >> 1);  // feats[lp][ptr]

    float2 PA[CH_], FA[CH_], PB[CH_], FB[CH_];

    auto issue = [&](float2 (&P)[CH_], float2 (&F)[CH_], int k0) {
      #pragma unroll
      for (int s = 0; s < CH_; ++s) {
        int k = k0 - s; if (k < 0) k = 0;     // clamped slots never used
        P[s] = *(const float2*)(ph + ((size_t)k * B_ + b) * T_ + 2 * lane);
        F[s] = *(const float2*)(fb + (size_t)k * T_ + 2 * lane);
      }
    };
    auto process = [&](const float2 (&P)[CH_], const float2 (&F)[CH_], int k0) {
      #pragma unroll
      for (int s = 0; s < CH_; ++s) {
        const int k = k0 - s;
        if (k >= 0) {
          // candidates c_i = fl(fl(ph_k[i]+trans[i,ptr]) + e), i = 2l, 2l+1
          const float2 tr = *(const float2*)(transT + ptr * TS_ + 2 * lane);
          float cx = (P[s].x + tr.x) + e;
          float cy = (P[s].y + tr.y) + e;
          unsigned long long q0 = __ballot(cx == tg);
          unsigned long long q1 = __ballot(cy == tg);
          int a0 = q0 ? 2 * (__ffsll(q0) - 1)     : (1 << 30);
          int a1 = q1 ? 2 * (__ffsll(q1) - 1) + 1 : (1 << 30);
          ptr = min(a0, a1);
          if (lane == 0) out[b * S_ + k] = ptr;
          // next step (k-1) targets ph_k[ptr], feats[k][ptr]
          tg = readlane_f((ptr & 1) ? P[s].y : P[s].x, ptr >> 1);
          e  = readlane_f((ptr & 1) ? F[s].y : F[s].x, ptr >> 1);
        }
      }
    };

    issue(PA, FA, lp - 1);
    for (int k0 = lp - 1; k0 >= 0; k0 -= 2 * CH_) {
      issue(PB, FB, k0 - CH_);
      process(PA, FA, k0);
      issue(PA, FA, k0 - 2 * CH_);
      process(PB, FB, k0 - CH_);
    }
  }
}

extern "C" void kernel_launch(void* const* d_in, const int* in_sizes, int n_in,
                              void* d_out, int out_size, void* d_ws, size_t ws_size,
                              hipStream_t stream) {
  const float* feats = (const float*)d_in[0];   // (B,S,T) fp32
  const void*  mask  = d_in[1];                 // (B,S) bool-ish
  const float* trans = (const float*)d_in[2];   // (T,T) fp32
  float* ph = (float*)d_ws;                     // (S,B,T) fp32 = 64 MB
  int*   out = (int*)d_out;                     // (B,S) int32

  viterbi_forward<<<dim3(B_), dim3(1024), 0, stream>>>(feats, trans, ph);
  viterbi_trace  <<<dim3(B_), dim3(64), 0, stream>>>(feats, mask, trans, ph, out);
}